// Round 6
// baseline (469.753 us; speedup 1.0000x reference)
//
#include <hip/hip_runtime.h>
#include <math.h>

#define NB 8
#define CDIM 512
#define NT 1024
#define MT 256
#define DFFI 2048   // GEGLU inner half

typedef short bf16x8 __attribute__((ext_vector_type(8)));
typedef float f32x4 __attribute__((ext_vector_type(4)));

__device__ __forceinline__ float sigmoidf_(float v){ return 1.0f/(1.0f+__expf(-v)); }

__device__ __forceinline__ short f2bf(float f){
    union { float f; unsigned u; } v; v.f = f;
    unsigned r = v.u + 0x7FFFu + ((v.u >> 16) & 1u);
    return (short)(r >> 16);
}

#define GLDS(gp, lp) __builtin_amdgcn_global_load_lds( \
    (const __attribute__((address_space(1))) void*)(gp), \
    (__attribute__((address_space(3))) void*)(lp), 16, 0, 0)

// ---------------- fused f32 -> bf16 weight conversion (single launch) ----------------
__global__ void cvt_all(const float* __restrict__ a1wq, const float* __restrict__ a1wk,
                        const float* __restrict__ a1wv, const float* __restrict__ a1wo,
                        const float* __restrict__ a2wq, const float* __restrict__ a2wk,
                        const float* __restrict__ a2wv, const float* __restrict__ a2wo,
                        const float* __restrict__ ffw1, const float* __restrict__ ffw2,
                        const float* __restrict__ convw, short* __restrict__ WB){
    int e = (blockIdx.x*256 + threadIdx.x)*8;
    if (e >= 5505024) return;
    const float* src; int off;
    if (e < 2097152){
        const float* tbl[8] = {a1wq,a1wk,a1wv,a1wo,a2wq,a2wk,a2wv,a2wo};
        src = tbl[e >> 18]; off = e & 262143;
    } else if (e < 4194304){ src = ffw1; off = e - 2097152; }
    else if (e < 5242880){ src = ffw2; off = e - 4194304; }
    else { src = convw; off = e - 5242880; }
    float4 x0 = ((const float4*)(src+off))[0], x1 = ((const float4*)(src+off))[1];
    bf16x8 v;
    v[0]=f2bf(x0.x); v[1]=f2bf(x0.y); v[2]=f2bf(x0.z); v[3]=f2bf(x0.w);
    v[4]=f2bf(x1.x); v[5]=f2bf(x1.y); v[6]=f2bf(x1.z); v[7]=f2bf(x1.w);
    *(bf16x8*)(WB + e) = v;
}

// ---------------- small elementwise / norm kernels ----------------

__global__ void emb_gemm(const float* __restrict__ emb, const float* __restrict__ w,
                         const float* __restrict__ bias, float* __restrict__ out){
    int idx = blockIdx.x*256 + threadIdx.x;   // 8*1024 total
    int b = idx >> 10, o = idx & 1023;
    const float* e = emb + b*128;
    const float* wr = w + (size_t)o*128;
    float acc = 0.f;
    for (int i=0;i<128;i++){ float ev=e[i]; acc += (ev*sigmoidf_(ev))*wr[i]; }
    out[idx] = acc + bias[o];
}

__global__ void gn_stats(const float* __restrict__ x, float* __restrict__ stats){
    int bg = blockIdx.x;               // b*32+g
    const float* base = x + (size_t)bg*16*NT;
    float s=0.f, sq=0.f;
    for (int i=threadIdx.x; i<16*NT; i+=256){ float v = base[i]; s+=v; sq+=v*v; }
    __shared__ float rs[256], rq[256];
    rs[threadIdx.x]=s; rq[threadIdx.x]=sq; __syncthreads();
    for (int st=128; st>0; st>>=1){
        if (threadIdx.x<st){ rs[threadIdx.x]+=rs[threadIdx.x+st]; rq[threadIdx.x]+=rq[threadIdx.x+st]; }
        __syncthreads();
    }
    if (threadIdx.x==0){
        float mu = rs[0]/(16.f*NT);
        float var = rq[0]/(16.f*NT) - mu*mu;
        stats[2*bg] = mu; stats[2*bg+1] = rsqrtf(var + 1e-6f);
    }
}

__global__ void mod_act(const float* __restrict__ x, const float* __restrict__ stats,
                        const float* __restrict__ gg, const float* __restrict__ gb,
                        const float* __restrict__ ss, short* __restrict__ act_t){
    __shared__ float tile[32][33];
    int n0 = blockIdx.x*32, c0 = blockIdx.y*32, b = blockIdx.z;
    int tx = threadIdx.x, ty = threadIdx.y;
    #pragma unroll
    for (int k=0;k<4;k++){
        int c = c0 + ty + k*8;
        tile[ty+k*8][tx] = x[((size_t)(b*CDIM+c))*NT + n0 + tx];
    }
    __syncthreads();
    #pragma unroll
    for (int k=0;k<4;k++){
        int c = c0 + tx, n = n0 + ty + k*8;
        float raw = tile[tx][ty+k*8];
        int gi = b*32 + (c>>4);
        float v = (raw - stats[2*gi]) * stats[2*gi+1] * gg[c] + gb[c];
        v = v * (1.f + ss[b*1024 + c]) + ss[b*1024 + 512 + c];
        act_t[((size_t)(b*NT+n))*CDIM + c] = f2bf(v * sigmoidf_(v));
    }
}

// LayerNorm: one wave per row (512 cols), 4 rows/block, shuffle reduce
__global__ void ln_rows(const float* __restrict__ in, const float* __restrict__ g,
                        const float* __restrict__ bta, short* __restrict__ out){
    int row = blockIdx.x*4 + (threadIdx.x>>6);
    int lane = threadIdx.x & 63;
    const float* base = in + (size_t)row*CDIM + lane*8;
    float4 a = ((const float4*)base)[0], b4 = ((const float4*)base)[1];
    float vals[8] = {a.x,a.y,a.z,a.w,b4.x,b4.y,b4.z,b4.w};
    float s = 0.f, q = 0.f;
    #pragma unroll
    for (int i=0;i<8;i++){ s += vals[i]; q += vals[i]*vals[i]; }
    #pragma unroll
    for (int off=32; off>0; off>>=1){ s += __shfl_xor(s, off); q += __shfl_xor(q, off); }
    float mu = s*(1.f/512.f);
    float rstd = rsqrtf(q*(1.f/512.f) - mu*mu + 1e-5f);
    const float* gp = g + lane*8;
    const float* bp = bta + lane*8;
    float4 g0=((const float4*)gp)[0], g1=((const float4*)gp)[1];
    float4 e0=((const float4*)bp)[0], e1=((const float4*)bp)[1];
    float gs[8] = {g0.x,g0.y,g0.z,g0.w,g1.x,g1.y,g1.z,g1.w};
    float es[8] = {e0.x,e0.y,e0.z,e0.w,e1.x,e1.y,e1.z,e1.w};
    bf16x8 o8;
    #pragma unroll
    for (int i=0;i<8;i++) o8[i] = f2bf((vals[i]-mu)*rstd*gs[i] + es[i]);
    *(bf16x8*)(out + (size_t)row*CDIM + lane*8) = o8;
}

__global__ void transpose_ctx(const float* __restrict__ in, short* __restrict__ out){
    __shared__ float tile[32][33];
    int m0 = blockIdx.x*32, c0 = blockIdx.y*32, b = blockIdx.z;
    int tx=threadIdx.x, ty=threadIdx.y;
    #pragma unroll
    for (int k=0;k<4;k++){
        int c = c0+ty+k*8;
        tile[ty+k*8][tx] = in[((size_t)(b*512+c))*MT + m0+tx];
    }
    __syncthreads();
    #pragma unroll
    for (int k=0;k<4;k++){
        int m = m0+ty+k*8, c = c0+tx;
        out[((size_t)(b*MT+m))*512 + c] = f2bf(tile[tx][ty+k*8]);
    }
}

__global__ void transpose_out(const float* __restrict__ in, float* __restrict__ out){
    __shared__ float tile[32][33];
    int n0 = blockIdx.x*32, c0 = blockIdx.y*32, b=blockIdx.z;
    int tx=threadIdx.x, ty=threadIdx.y;
    #pragma unroll
    for (int k=0;k<4;k++){
        int n = n0+ty+k*8;
        tile[ty+k*8][tx] = in[((size_t)(b*NT+n))*512 + c0+tx];
    }
    __syncthreads();
    #pragma unroll
    for (int k=0;k<4;k++){
        int c = c0+ty+k*8, n = n0+tx;
        out[((size_t)(b*512+c))*NT + n] = tile[tx][ty+k*8];
    }
}

// ---------------- bf16 GEMM: 128x64 tile, BK=64, double-buffered GLDS pipeline ----------------
// Prefetch next K-tile before waiting: s_waitcnt vmcnt(6) + raw s_barrier keeps 6 loads
// in flight across the barrier (AITER-style; __syncthreads would force vmcnt(0)).
__global__ __launch_bounds__(256,2) void gemm_bb(
        const short* __restrict__ A, const short* __restrict__ W,
        const float* __restrict__ bias, const float* __restrict__ res,
        float* __restrict__ outf, short* __restrict__ outb,
        int K, int O, int ostr, int resmode){
    __shared__ short As[2][128*64];
    __shared__ short Bs[2][64*64];
    int r0 = blockIdx.x*128, o0 = blockIdx.y*64;
    int tid = threadIdx.x, w = tid>>6, lane = tid&63;
    int quad = lane>>4, lw = lane&15;
    int g_row = lane>>3, g_s = lane&7;
    int sseg = g_s ^ g_row;
    int wr = (w&1)*64, wc = (w>>1)*32;
    const short* Abase = A + (size_t)r0*K;
    const short* Wbase = W + (size_t)o0*K;
    f32x4 acc[4][2] = {};

    auto issue = [&](int buf, int kk){
        #pragma unroll
        for (int j=0;j<4;j++){
            int row = w*32 + j*8 + g_row;
            GLDS(Abase + (size_t)row*K + kk + sseg*8, &As[buf][(w*32+j*8)*64]);
        }
        #pragma unroll
        for (int j=0;j<2;j++){
            int row = w*16 + j*8 + g_row;
            GLDS(Wbase + (size_t)row*K + kk + sseg*8, &Bs[buf][(w*16+j*8)*64]);
        }
    };

    issue(0, 0);
    int nk = K >> 6;
    for (int it=0; it<nk; ++it){
        int cur = it & 1;
        if (it+1 < nk){
            issue(cur^1, (it+1)<<6);
            __asm__ volatile("s_waitcnt vmcnt(6)" ::: "memory");
        } else {
            __asm__ volatile("s_waitcnt vmcnt(0)" ::: "memory");
        }
        __builtin_amdgcn_s_barrier();
        bf16x8 af[4][2], bf[2][2];
        #pragma unroll
        for (int ks=0; ks<2; ks++){
            #pragma unroll
            for (int i=0;i<4;i++){
                int row = wr + i*16 + lw;
                af[i][ks] = *(const bf16x8*)&As[cur][row*64 + (((ks*4+quad) ^ (lw&7)))*8];
            }
            #pragma unroll
            for (int j=0;j<2;j++){
                int col = wc + j*16 + lw;
                bf[j][ks] = *(const bf16x8*)&Bs[cur][col*64 + (((ks*4+quad) ^ (lw&7)))*8];
            }
        }
        #pragma unroll
        for (int ks=0; ks<2; ks++)
            #pragma unroll
            for (int i=0;i<4;i++)
                #pragma unroll
                for (int j=0;j<2;j++)
                    acc[i][j] = __builtin_amdgcn_mfma_f32_16x16x32_bf16(af[i][ks], bf[j][ks], acc[i][j], 0, 0, 0);
        __asm__ volatile("s_waitcnt lgkmcnt(0)" ::: "memory");
        __builtin_amdgcn_s_barrier();
    }
    #pragma unroll
    for (int i=0;i<4;i++){
        #pragma unroll
        for (int j=0;j<2;j++){
            #pragma unroll
            for (int reg=0; reg<4; reg++){
                int row = r0 + wr + i*16 + quad*4 + reg;
                int col = o0 + wc + j*16 + lw;
                float v = acc[i][j][reg];
                if (bias) v += bias[col];
                if (resmode==1) v += res[(size_t)row*O + col];
                else if (resmode==2){
                    int b = row >> 10, n = row & 1023;
                    v += res[((size_t)(b*CDIM+col))*NT + n];
                }
                if (outf) outf[(size_t)row*ostr + col] = v;
                else      outb[(size_t)row*ostr + col] = f2bf(v);
            }
        }
    }
}

// ---------------- FF1 fused GEGLU, 128x64 tile (x2 gates), BK=64 ----------------
__global__ __launch_bounds__(256,2) void ff1_geglu_bb(
        const short* __restrict__ A, const short* __restrict__ W,
        const float* __restrict__ b1, short* __restrict__ out){
    __shared__ short As[128*64];
    __shared__ short Ba[64*64];
    __shared__ short Bg[64*64];
    int r0 = blockIdx.x*128, j0 = blockIdx.y*64;
    int tid = threadIdx.x, w = tid>>6, lane = tid&63;
    int quad = lane>>4, lw = lane&15;
    int g_row = lane>>3, g_s = lane&7;
    int sseg = g_s ^ g_row;
    int wr = (w&1)*64, wc = (w>>1)*32;
    f32x4 acca[4][2] = {}, accg[4][2] = {};
    for (int k0 = 0; k0 < 512; k0 += 64){
        #pragma unroll
        for (int j=0;j<4;j++){
            int row = w*32 + j*8 + g_row;
            GLDS(A + (size_t)(r0+row)*512 + k0 + sseg*8, As + (w*32+j*8)*64);
        }
        #pragma unroll
        for (int j=0;j<2;j++){
            int row = w*16 + j*8 + g_row;
            GLDS(W + (size_t)(j0+row)*512 + k0 + sseg*8, Ba + (w*16+j*8)*64);
            GLDS(W + (size_t)(2048+j0+row)*512 + k0 + sseg*8, Bg + (w*16+j*8)*64);
        }
        __syncthreads();
        bf16x8 af[4][2], ba[2][2], bg[2][2];
        #pragma unroll
        for (int ks=0; ks<2; ks++){
            #pragma unroll
            for (int i=0;i<4;i++){
                int row = wr + i*16 + lw;
                af[i][ks] = *(const bf16x8*)&As[row*64 + (((ks*4+quad) ^ (lw&7)))*8];
            }
            #pragma unroll
            for (int j=0;j<2;j++){
                int col = wc + j*16 + lw;
                ba[j][ks] = *(const bf16x8*)&Ba[col*64 + (((ks*4+quad) ^ (lw&7)))*8];
                bg[j][ks] = *(const bf16x8*)&Bg[col*64 + (((ks*4+quad) ^ (lw&7)))*8];
            }
        }
        #pragma unroll
        for (int ks=0; ks<2; ks++)
            #pragma unroll
            for (int i=0;i<4;i++)
                #pragma unroll
                for (int j=0;j<2;j++){
                    acca[i][j] = __builtin_amdgcn_mfma_f32_16x16x32_bf16(af[i][ks], ba[j][ks], acca[i][j], 0, 0, 0);
                    accg[i][j] = __builtin_amdgcn_mfma_f32_16x16x32_bf16(af[i][ks], bg[j][ks], accg[i][j], 0, 0, 0);
                }
        __syncthreads();
    }
    #pragma unroll
    for (int i=0;i<4;i++){
        #pragma unroll
        for (int j=0;j<2;j++){
            #pragma unroll
            for (int reg=0; reg<4; reg++){
                int row = r0 + wr + i*16 + quad*4 + reg;
                int col = j0 + wc + j*16 + lw;
                float a = acca[i][j][reg] + b1[col];
                float g = accg[i][j][reg] + b1[2048+col];
                float gl = 0.5f*g*(1.0f + erff(g*0.70710678118654752f));
                out[(size_t)row*DFFI + col] = f2bf(a*gl);
            }
        }
    }
}

// ---------------- flash attention: GLDS staging, global V^T, no-max softmax ----------------
__global__ __launch_bounds__(256) void attn_fa(
        const short* __restrict__ q, const short* __restrict__ k,
        const short* __restrict__ vt, short* __restrict__ o,
        int Nq, int Nk, int qstr, int kstr, int vtstr, float sc_log2e){
    __shared__ short Ks[64*64];
    __shared__ short Vs[64*64];
    __shared__ short QP[64*64];   // Qs (start) then Ps (loop) — both wave-local rows
    int bh = blockIdx.x & 63;
    int qt = blockIdx.x >> 6;
    int b = bh >> 3, h = bh & 7;
    int tid = threadIdx.x, w = tid>>6, lane = tid&63;
    int quad = lane>>4, lw = lane&15;
    int lrow = lane>>3, lg = (lane&7) ^ (lane>>3);
    int q0 = qt*64;

    #pragma unroll
    for (int t=0;t<2;t++){
        int row = w*16 + t*8 + lrow;
        GLDS(q + (size_t)(b*Nq + q0 + row)*qstr + h*64 + lg*8, QP + (w*16+t*8)*64);
    }
    __syncthreads();
    bf16x8 qf[2];
    {
        int r = w*16 + lw;
        qf[0] = *(const bf16x8*)&QP[r*64 + (( quad      ^ (r&7))*8)];
        qf[1] = *(const bf16x8*)&QP[r*64 + (((quad+4) ^ (r&7))*8)];
    }

    f32x4 oacc[4] = {};
    f32x4 accl = {};
    bf16x8 ones;
    #pragma unroll
    for (int i=0;i<8;i++) ones[i] = (short)0x3F80;

    int nkt = Nk >> 6;
    for (int kt = 0; kt < nkt; kt++){
        __syncthreads();
        #pragma unroll
        for (int t=0;t<2;t++){
            int row = w*16 + t*8 + lrow;
            GLDS(k  + (size_t)(b*Nk + kt*64 + row)*kstr + h*64 + lg*8, Ks + (w*16+t*8)*64);
            GLDS(vt + (size_t)(h*64 + row)*vtstr + b*Nk + kt*64 + lg*8, Vs + (w*16+t*8)*64);
        }
        __syncthreads();

        f32x4 s[4] = {};
        #pragma unroll
        for (int ct=0;ct<4;ct++){
            int r = ct*16 + lw;
            bf16x8 kf0 = *(const bf16x8*)&Ks[r*64 + (( quad      ^ (r&7))*8)];
            bf16x8 kf1 = *(const bf16x8*)&Ks[r*64 + (((quad+4) ^ (r&7))*8)];
            s[ct] = __builtin_amdgcn_mfma_f32_16x16x32_bf16(qf[0], kf0, s[ct], 0,0,0);
            s[ct] = __builtin_amdgcn_mfma_f32_16x16x32_bf16(qf[1], kf1, s[ct], 0,0,0);
        }

        #pragma unroll
        for (int ct=0;ct<4;ct++){
            int colb = (((ct+quad)&3)*16) + lw;
            #pragma unroll
            for (int r=0;r<4;r++){
                float p = exp2f(s[ct][r]*sc_log2e);
                union { float f; unsigned u; } uv; uv.f = p;
                QP[(w*16 + quad*4 + r)*64 + colb] = (short)(uv.u >> 16);
            }
        }
        __asm__ volatile("s_waitcnt lgkmcnt(0)" ::: "memory");

        bf16x8 pf[2];
        {
            int r = w*16 + lw;
            int rot = (lw>>2)&3;
            pf[0] = *(const bf16x8*)&QP[r*64 + (((    (quad>>1) + rot)&3)*16) + (quad&1)*8];
            pf[1] = *(const bf16x8*)&QP[r*64 + (((2 + (quad>>1) + rot)&3)*16) + (quad&1)*8];
        }
        accl = __builtin_amdgcn_mfma_f32_16x16x32_bf16(pf[0], ones, accl, 0,0,0);
        accl = __builtin_amdgcn_mfma_f32_16x16x32_bf16(pf[1], ones, accl, 0,0,0);
        #pragma unroll
        for (int dt=0; dt<4; dt++){
            int r = dt*16 + lw;
            bf16x8 vf0 = *(const bf16x8*)&Vs[r*64 + (( quad      ^ (r&7))*8)];
            bf16x8 vf1 = *(const bf16x8*)&Vs[r*64 + (((quad+4) ^ (r&7))*8)];
            oacc[dt] = __builtin_amdgcn_mfma_f32_16x16x32_bf16(pf[0], vf0, oacc[dt], 0,0,0);
            oacc[dt] = __builtin_amdgcn_mfma_f32_16x16x32_bf16(pf[1], vf1, oacc[dt], 0,0,0);
        }
    }
    float inv[4];
    #pragma unroll
    for (int r=0;r<4;r++) inv[r] = 1.0f/accl[r];
    #pragma unroll
    for (int dt=0; dt<4; dt++){
        #pragma unroll
        for (int r=0;r<4;r++){
            int qi = q0 + w*16 + quad*4 + r;
            o[(size_t)(b*Nq + qi)*512 + h*64 + dt*16 + lw] = f2bf(oacc[dt][r]*inv[r]);
        }
    }
}

extern "C" void kernel_launch(void* const* d_in, const int* in_sizes, int n_in,
                              void* d_out, int out_size, void* d_ws, size_t ws_size,
                              hipStream_t stream) {
    const float* x      = (const float*)d_in[0];
    const float* emb    = (const float*)d_in[1];
    const float* context= (const float*)d_in[2];
    const float* w_emb  = (const float*)d_in[3];
    const float* b_emb  = (const float*)d_in[4];
    const float* gn_g   = (const float*)d_in[5];
    const float* gn_b   = (const float*)d_in[6];
    const float* conv_w = (const float*)d_in[7];
    const float* conv_b = (const float*)d_in[8];
    const float* a1_wq  = (const float*)d_in[9];
    const float* a1_wk  = (const float*)d_in[10];
    const float* a1_wv  = (const float*)d_in[11];
    const float* a1_wo  = (const float*)d_in[12];
    const float* a1_bo  = (const float*)d_in[13];
    const float* a2_wq  = (const float*)d_in[14];
    const float* a2_wk  = (const float*)d_in[15];
    const float* a2_wv  = (const float*)d_in[16];
    const float* a2_wo  = (const float*)d_in[17];
    const float* a2_bo  = (const float*)d_in[18];
    const float* ln1_g  = (const float*)d_in[19];
    const float* ln1_b  = (const float*)d_in[20];
    const float* ln2_g  = (const float*)d_in[21];
    const float* ln2_b  = (const float*)d_in[22];
    const float* ln3_g  = (const float*)d_in[23];
    const float* ln3_b  = (const float*)d_in[24];
    const float* ff_w1  = (const float*)d_in[25];
    const float* ff_b1  = (const float*)d_in[26];
    const float* ff_w2  = (const float*)d_in[27];
    const float* ff_b2  = (const float*)d_in[28];
    float* out = (float*)d_out;

    char* base = (char*)d_ws;
    float* SS    = (float*)base;                 // 8192 f
    float* STATS = SS + 8192;                    // 512 f
    float* F0    = (float*)(base + 65536);       // [8192,512] f32 residual
    float* F1    = F0 + 4194304;
    short* WB    = (short*)(F1 + 4194304);       // bf16 weights, 5505024 shorts
    short* qkW   = WB;                           // [1024,512]: a1_wq, a1_wk
    short* vW    = WB + 524288;                  // [512,512]
    short* wo1W  = WB + 786432;
    short* a2qW  = WB + 1048576;
    short* a2kW  = WB + 1310720;
    short* a2vW  = WB + 1572864;
    short* wo2W  = WB + 1835008;
    short* ffw1W = WB + 2097152;                 // [4096,512]
    short* ffw2W = WB + 4194304;                 // [512,2048]
    short* convW = WB + 5242880;
    short* CTXb  = WB + 5505024;                 // [2048,512]
    short* L0    = CTXb + 1048576;               // [8192,512]
    short* BIG   = L0 + 4194304;                 // multi-purpose
    short* Q0    = BIG;                          // [8192,1024]: q | k
    short* VT1   = BIG + 8388608;                // [512,8192] V^T (self)
    short* AO    = BIG + 12582912;               // [8192,512]
    short* A2Q   = BIG;                          // [8192,512]
    short* K2    = BIG + 4194304;                // [2048,512]
    short* VT2   = BIG + 5242880;                // [512,2048]
    short* ACT2  = BIG;                          // [8192,2048]

    dim3 tb(32,8);
    const float SCL2E = 0.125f * 1.4426950408889634f;

    // ---- weights -> bf16 (one launch) ----
    cvt_all<<<2688,256,0,stream>>>(a1_wq,a1_wk,a1_wv,a1_wo,a2_wq,a2_wk,a2_wv,a2_wo,
                                   ff_w1,ff_w2,conv_w, WB);

    // ---- residual conv branch ----
    emb_gemm<<<32,256,0,stream>>>(emb, w_emb, b_emb, SS);
    gn_stats<<<256,256,0,stream>>>(x, STATS);
    mod_act<<<dim3(32,16,8), tb, 0, stream>>>(x, STATS, gn_g, gn_b, SS, L0);
    transpose_ctx<<<dim3(8,16,8), tb, 0, stream>>>(context, CTXb);
    gemm_bb<<<dim3(64,8),256,0,stream>>>(L0, convW, conv_b, x, F0, nullptr, 512, 512, 512, 2);  // xt0=F0

    // ---- self attention ----
    ln_rows<<<2048,256,0,stream>>>(F0, ln1_g, ln1_b, L0);
    gemm_bb<<<dim3(64,16),256,0,stream>>>(L0, qkW, nullptr, nullptr, nullptr, Q0, 512, 1024, 1024, 0);
    gemm_bb<<<dim3(4,128),256,0,stream>>>(vW, L0, nullptr, nullptr, nullptr, VT1, 512, 8192, 8192, 0); // V^T
    attn_fa<<<1024,256,0,stream>>>(Q0, Q0+512, VT1, AO, 1024, 1024, 1024, 1024, 8192, SCL2E);
    gemm_bb<<<dim3(64,8),256,0,stream>>>(AO, wo1W, a1_bo, F0, F1, nullptr, 512, 512, 512, 1);   // xt1=F1

    // ---- cross attention ----
    ln_rows<<<2048,256,0,stream>>>(F1, ln2_g, ln2_b, L0);
    gemm_bb<<<dim3(64,8),256,0,stream>>>(L0, a2qW, nullptr, nullptr, nullptr, A2Q, 512, 512, 512, 0);
    gemm_bb<<<dim3(16,8),256,0,stream>>>(CTXb, a2kW, nullptr, nullptr, nullptr, K2, 512, 512, 512, 0);
    gemm_bb<<<dim3(4,32),256,0,stream>>>(a2vW, CTXb, nullptr, nullptr, nullptr, VT2, 512, 2048, 2048, 0); // V^T
    attn_fa<<<1024,256,0,stream>>>(A2Q, K2, VT2, AO, 1024, 256, 512, 512, 2048, SCL2E);
    gemm_bb<<<dim3(64,8),256,0,stream>>>(AO, wo2W, a2_bo, F1, F0, nullptr, 512, 512, 512, 1);   // xt2=F0

    // ---- GEGLU FF ----
    ln_rows<<<2048,256,0,stream>>>(F0, ln3_g, ln3_b, L0);
    ff1_geglu_bb<<<dim3(64,32),256,0,stream>>>(L0, ffw1W, ff_b1, ACT2);
    gemm_bb<<<dim3(64,8),256,0,stream>>>(ACT2, ffw2W, ff_b2, F0, F1, nullptr, 2048, 512, 512, 1);
    transpose_out<<<dim3(32,16,8), tb, 0, stream>>>(F1, out);
}

// Round 7
// 441.741 us; speedup vs baseline: 1.0634x; 1.0634x over previous
//
#include <hip/hip_runtime.h>
#include <math.h>

#define NB 8
#define CDIM 512
#define NT 1024
#define MT 256
#define DFFI 2048   // GEGLU inner half

typedef short bf16x8 __attribute__((ext_vector_type(8)));
typedef float f32x4 __attribute__((ext_vector_type(4)));

__device__ __forceinline__ float sigmoidf_(float v){ return 1.0f/(1.0f+__expf(-v)); }

__device__ __forceinline__ short f2bf(float f){
    union { float f; unsigned u; } v; v.f = f;
    unsigned r = v.u + 0x7FFFu + ((v.u >> 16) & 1u);
    return (short)(r >> 16);
}

#define GLDS(gp, lp) __builtin_amdgcn_global_load_lds( \
    (const __attribute__((address_space(1))) void*)(gp), \
    (__attribute__((address_space(3))) void*)(lp), 16, 0, 0)

// ---------------- fused f32 -> bf16 weight conversion (single launch) ----------------
__global__ void cvt_all(const float* __restrict__ a1wq, const float* __restrict__ a1wk,
                        const float* __restrict__ a1wv, const float* __restrict__ a1wo,
                        const float* __restrict__ a2wq, const float* __restrict__ a2wk,
                        const float* __restrict__ a2wv, const float* __restrict__ a2wo,
                        const float* __restrict__ ffw1, const float* __restrict__ ffw2,
                        const float* __restrict__ convw, short* __restrict__ WB){
    int e = (blockIdx.x*256 + threadIdx.x)*8;
    if (e >= 5505024) return;
    const float* src; int off;
    if (e < 2097152){
        const float* tbl[8] = {a1wq,a1wk,a1wv,a1wo,a2wq,a2wk,a2wv,a2wo};
        src = tbl[e >> 18]; off = e & 262143;
    } else if (e < 4194304){ src = ffw1; off = e - 2097152; }
    else if (e < 5242880){ src = ffw2; off = e - 4194304; }
    else { src = convw; off = e - 5242880; }
    float4 x0 = ((const float4*)(src+off))[0], x1 = ((const float4*)(src+off))[1];
    bf16x8 v;
    v[0]=f2bf(x0.x); v[1]=f2bf(x0.y); v[2]=f2bf(x0.z); v[3]=f2bf(x0.w);
    v[4]=f2bf(x1.x); v[5]=f2bf(x1.y); v[6]=f2bf(x1.z); v[7]=f2bf(x1.w);
    *(bf16x8*)(WB + e) = v;
}

// ---------------- small elementwise / norm kernels ----------------

__global__ void emb_gemm(const float* __restrict__ emb, const float* __restrict__ w,
                         const float* __restrict__ bias, float* __restrict__ out){
    int idx = blockIdx.x*256 + threadIdx.x;   // 8*1024 total
    int b = idx >> 10, o = idx & 1023;
    const float* e = emb + b*128;
    const float* wr = w + (size_t)o*128;
    float acc = 0.f;
    for (int i=0;i<128;i++){ float ev=e[i]; acc += (ev*sigmoidf_(ev))*wr[i]; }
    out[idx] = acc + bias[o];
}

__global__ void gn_stats(const float* __restrict__ x, float* __restrict__ stats){
    int bg = blockIdx.x;               // b*32+g
    const float* base = x + (size_t)bg*16*NT;
    float s=0.f, sq=0.f;
    for (int i=threadIdx.x; i<16*NT; i+=256){ float v = base[i]; s+=v; sq+=v*v; }
    __shared__ float rs[256], rq[256];
    rs[threadIdx.x]=s; rq[threadIdx.x]=sq; __syncthreads();
    for (int st=128; st>0; st>>=1){
        if (threadIdx.x<st){ rs[threadIdx.x]+=rs[threadIdx.x+st]; rq[threadIdx.x]+=rq[threadIdx.x+st]; }
        __syncthreads();
    }
    if (threadIdx.x==0){
        float mu = rs[0]/(16.f*NT);
        float var = rq[0]/(16.f*NT) - mu*mu;
        stats[2*bg] = mu; stats[2*bg+1] = rsqrtf(var + 1e-6f);
    }
}

__global__ void mod_act(const float* __restrict__ x, const float* __restrict__ stats,
                        const float* __restrict__ gg, const float* __restrict__ gb,
                        const float* __restrict__ ss, short* __restrict__ act_t){
    __shared__ float tile[32][33];
    int n0 = blockIdx.x*32, c0 = blockIdx.y*32, b = blockIdx.z;
    int tx = threadIdx.x, ty = threadIdx.y;
    #pragma unroll
    for (int k=0;k<4;k++){
        int c = c0 + ty + k*8;
        tile[ty+k*8][tx] = x[((size_t)(b*CDIM+c))*NT + n0 + tx];
    }
    __syncthreads();
    #pragma unroll
    for (int k=0;k<4;k++){
        int c = c0 + tx, n = n0 + ty + k*8;
        float raw = tile[tx][ty+k*8];
        int gi = b*32 + (c>>4);
        float v = (raw - stats[2*gi]) * stats[2*gi+1] * gg[c] + gb[c];
        v = v * (1.f + ss[b*1024 + c]) + ss[b*1024 + 512 + c];
        act_t[((size_t)(b*NT+n))*CDIM + c] = f2bf(v * sigmoidf_(v));
    }
}

// LayerNorm: one wave per row (512 cols), 4 rows/block, shuffle reduce
__global__ void ln_rows(const float* __restrict__ in, const float* __restrict__ g,
                        const float* __restrict__ bta, short* __restrict__ out){
    int row = blockIdx.x*4 + (threadIdx.x>>6);
    int lane = threadIdx.x & 63;
    const float* base = in + (size_t)row*CDIM + lane*8;
    float4 a = ((const float4*)base)[0], b4 = ((const float4*)base)[1];
    float vals[8] = {a.x,a.y,a.z,a.w,b4.x,b4.y,b4.z,b4.w};
    float s = 0.f, q = 0.f;
    #pragma unroll
    for (int i=0;i<8;i++){ s += vals[i]; q += vals[i]*vals[i]; }
    #pragma unroll
    for (int off=32; off>0; off>>=1){ s += __shfl_xor(s, off); q += __shfl_xor(q, off); }
    float mu = s*(1.f/512.f);
    float rstd = rsqrtf(q*(1.f/512.f) - mu*mu + 1e-5f);
    const float* gp = g + lane*8;
    const float* bp = bta + lane*8;
    float4 g0=((const float4*)gp)[0], g1=((const float4*)gp)[1];
    float4 e0=((const float4*)bp)[0], e1=((const float4*)bp)[1];
    float gs[8] = {g0.x,g0.y,g0.z,g0.w,g1.x,g1.y,g1.z,g1.w};
    float es[8] = {e0.x,e0.y,e0.z,e0.w,e1.x,e1.y,e1.z,e1.w};
    bf16x8 o8;
    #pragma unroll
    for (int i=0;i<8;i++) o8[i] = f2bf((vals[i]-mu)*rstd*gs[i] + es[i]);
    *(bf16x8*)(out + (size_t)row*CDIM + lane*8) = o8;
}

__global__ void transpose_ctx(const float* __restrict__ in, short* __restrict__ out){
    __shared__ float tile[32][33];
    int m0 = blockIdx.x*32, c0 = blockIdx.y*32, b = blockIdx.z;
    int tx=threadIdx.x, ty=threadIdx.y;
    #pragma unroll
    for (int k=0;k<4;k++){
        int c = c0+ty+k*8;
        tile[ty+k*8][tx] = in[((size_t)(b*512+c))*MT + m0+tx];
    }
    __syncthreads();
    #pragma unroll
    for (int k=0;k<4;k++){
        int m = m0+ty+k*8, c = c0+tx;
        out[((size_t)(b*MT+m))*512 + c] = f2bf(tile[tx][ty+k*8]);
    }
}

__global__ void transpose_out(const float* __restrict__ in, float* __restrict__ out){
    __shared__ float tile[32][33];
    int n0 = blockIdx.x*32, c0 = blockIdx.y*32, b=blockIdx.z;
    int tx=threadIdx.x, ty=threadIdx.y;
    #pragma unroll
    for (int k=0;k<4;k++){
        int n = n0+ty+k*8;
        tile[ty+k*8][tx] = in[((size_t)(b*NT+n))*512 + c0+tx];
    }
    __syncthreads();
    #pragma unroll
    for (int k=0;k<4;k++){
        int c = c0+ty+k*8, n = n0+tx;
        out[((size_t)(b*512+c))*NT + n] = tile[tx][ty+k*8];
    }
}

// ---------------- bf16 GEMM: 128x64 tile, BK=64, single-buffered GLDS (for wide-O) ----------------
__global__ __launch_bounds__(256,2) void gemm_bb(
        const short* __restrict__ A, const short* __restrict__ W,
        const float* __restrict__ bias, const float* __restrict__ res,
        float* __restrict__ outf, short* __restrict__ outb,
        int K, int O, int ostr, int resmode){
    __shared__ short As[128*64];
    __shared__ short Bs[64*64];
    int r0 = blockIdx.x*128, o0 = blockIdx.y*64;
    int tid = threadIdx.x, w = tid>>6, lane = tid&63;
    int quad = lane>>4, lw = lane&15;
    int g_row = lane>>3, g_s = lane&7;
    int sseg = g_s ^ g_row;
    int wr = (w&1)*64, wc = (w>>1)*32;
    f32x4 acc[4][2] = {};
    for (int k0 = 0; k0 < K; k0 += 64){
        #pragma unroll
        for (int j=0;j<4;j++){
            int row = w*32 + j*8 + g_row;
            GLDS(A + (size_t)(r0+row)*K + k0 + sseg*8, As + (w*32+j*8)*64);
        }
        #pragma unroll
        for (int j=0;j<2;j++){
            int row = w*16 + j*8 + g_row;
            GLDS(W + (size_t)(o0+row)*K + k0 + sseg*8, Bs + (w*16+j*8)*64);
        }
        __syncthreads();
        bf16x8 af[4][2], bf[2][2];
        #pragma unroll
        for (int ks=0; ks<2; ks++){
            #pragma unroll
            for (int i=0;i<4;i++){
                int row = wr + i*16 + lw;
                af[i][ks] = *(const bf16x8*)&As[row*64 + (((ks*4+quad) ^ (lw&7)))*8];
            }
            #pragma unroll
            for (int j=0;j<2;j++){
                int col = wc + j*16 + lw;
                bf[j][ks] = *(const bf16x8*)&Bs[col*64 + (((ks*4+quad) ^ (lw&7)))*8];
            }
        }
        #pragma unroll
        for (int ks=0; ks<2; ks++)
            #pragma unroll
            for (int i=0;i<4;i++)
                #pragma unroll
                for (int j=0;j<2;j++)
                    acc[i][j] = __builtin_amdgcn_mfma_f32_16x16x32_bf16(af[i][ks], bf[j][ks], acc[i][j], 0, 0, 0);
        __syncthreads();
    }
    #pragma unroll
    for (int i=0;i<4;i++){
        #pragma unroll
        for (int j=0;j<2;j++){
            #pragma unroll
            for (int reg=0; reg<4; reg++){
                int row = r0 + wr + i*16 + quad*4 + reg;
                int col = o0 + wc + j*16 + lw;
                float v = acc[i][j][reg];
                if (bias) v += bias[col];
                if (resmode==1) v += res[(size_t)row*O + col];
                else if (resmode==2){
                    int b = row >> 10, n = row & 1023;
                    v += res[((size_t)(b*CDIM+col))*NT + n];
                }
                if (outf) outf[(size_t)row*ostr + col] = v;
                else      outb[(size_t)row*ostr + col] = f2bf(v);
            }
        }
    }
}

// ---------------- bf16 GEMM: 64x64 tile, BK=64 — max block-count for skinny outputs ----------------
// grid (M/64, O/64). 16 KB LDS, no launch_bounds cap -> 4+ blocks/CU where the grid allows.
__global__ __launch_bounds__(256) void gemm64(
        const short* __restrict__ A, const short* __restrict__ W,
        const float* __restrict__ bias, const float* __restrict__ res,
        float* __restrict__ outf, short* __restrict__ outb,
        int K, int O, int ostr, int resmode){
    __shared__ short As[64*64];
    __shared__ short Bs[64*64];
    int r0 = blockIdx.x*64, o0 = blockIdx.y*64;
    int tid = threadIdx.x, w = tid>>6, lane = tid&63;
    int quad = lane>>4, lw = lane&15;
    int lrow = lane>>3, lg = (lane&7) ^ (lane>>3);   // staged seg = lg ^ row&7 handled by XOR
    int wr = (w&1)*32, wc = (w>>1)*32;
    f32x4 acc[2][2] = {};
    for (int k0 = 0; k0 < K; k0 += 64){
        #pragma unroll
        for (int t=0;t<2;t++){
            int row = w*16 + t*8 + lrow;
            GLDS(A + (size_t)(r0+row)*K + k0 + lg*8, As + (w*16+t*8)*64);
            GLDS(W + (size_t)(o0+row)*K + k0 + lg*8, Bs + (w*16+t*8)*64);
        }
        __syncthreads();
        bf16x8 af[2][2], bf[2][2];
        #pragma unroll
        for (int ks=0; ks<2; ks++){
            #pragma unroll
            for (int i=0;i<2;i++){
                int row = wr + i*16 + lw;
                af[i][ks] = *(const bf16x8*)&As[row*64 + (((ks*4+quad) ^ (lw&7)))*8];
                int col = wc + i*16 + lw;
                bf[i][ks] = *(const bf16x8*)&Bs[col*64 + (((ks*4+quad) ^ (lw&7)))*8];
            }
        }
        #pragma unroll
        for (int ks=0; ks<2; ks++)
            #pragma unroll
            for (int i=0;i<2;i++)
                #pragma unroll
                for (int j=0;j<2;j++)
                    acc[i][j] = __builtin_amdgcn_mfma_f32_16x16x32_bf16(af[i][ks], bf[j][ks], acc[i][j], 0, 0, 0);
        __syncthreads();
    }
    #pragma unroll
    for (int i=0;i<2;i++){
        #pragma unroll
        for (int j=0;j<2;j++){
            #pragma unroll
            for (int reg=0; reg<4; reg++){
                int row = r0 + wr + i*16 + quad*4 + reg;
                int col = o0 + wc + j*16 + lw;
                float v = acc[i][j][reg];
                if (bias) v += bias[col];
                if (resmode==1) v += res[(size_t)row*O + col];
                else if (resmode==2){
                    int b = row >> 10, n = row & 1023;
                    v += res[((size_t)(b*CDIM+col))*NT + n];
                }
                if (outf) outf[(size_t)row*ostr + col] = v;
                else      outb[(size_t)row*ostr + col] = f2bf(v);
            }
        }
    }
}

// ---------------- FF1 fused GEGLU, 128x64 tile (x2 gates), BK=64 ----------------
__global__ __launch_bounds__(256,2) void ff1_geglu_bb(
        const short* __restrict__ A, const short* __restrict__ W,
        const float* __restrict__ b1, short* __restrict__ out){
    __shared__ short As[128*64];
    __shared__ short Ba[64*64];
    __shared__ short Bg[64*64];
    int r0 = blockIdx.x*128, j0 = blockIdx.y*64;
    int tid = threadIdx.x, w = tid>>6, lane = tid&63;
    int quad = lane>>4, lw = lane&15;
    int g_row = lane>>3, g_s = lane&7;
    int sseg = g_s ^ g_row;
    int wr = (w&1)*64, wc = (w>>1)*32;
    f32x4 acca[4][2] = {}, accg[4][2] = {};
    for (int k0 = 0; k0 < 512; k0 += 64){
        #pragma unroll
        for (int j=0;j<4;j++){
            int row = w*32 + j*8 + g_row;
            GLDS(A + (size_t)(r0+row)*512 + k0 + sseg*8, As + (w*32+j*8)*64);
        }
        #pragma unroll
        for (int j=0;j<2;j++){
            int row = w*16 + j*8 + g_row;
            GLDS(W + (size_t)(j0+row)*512 + k0 + sseg*8, Ba + (w*16+j*8)*64);
            GLDS(W + (size_t)(2048+j0+row)*512 + k0 + sseg*8, Bg + (w*16+j*8)*64);
        }
        __syncthreads();
        bf16x8 af[4][2], ba[2][2], bg[2][2];
        #pragma unroll
        for (int ks=0; ks<2; ks++){
            #pragma unroll
            for (int i=0;i<4;i++){
                int row = wr + i*16 + lw;
                af[i][ks] = *(const bf16x8*)&As[row*64 + (((ks*4+quad) ^ (lw&7)))*8];
            }
            #pragma unroll
            for (int j=0;j<2;j++){
                int col = wc + j*16 + lw;
                ba[j][ks] = *(const bf16x8*)&Ba[col*64 + (((ks*4+quad) ^ (lw&7)))*8];
                bg[j][ks] = *(const bf16x8*)&Bg[col*64 + (((ks*4+quad) ^ (lw&7)))*8];
            }
        }
        #pragma unroll
        for (int ks=0; ks<2; ks++)
            #pragma unroll
            for (int i=0;i<4;i++)
                #pragma unroll
                for (int j=0;j<2;j++){
                    acca[i][j] = __builtin_amdgcn_mfma_f32_16x16x32_bf16(af[i][ks], ba[j][ks], acca[i][j], 0, 0, 0);
                    accg[i][j] = __builtin_amdgcn_mfma_f32_16x16x32_bf16(af[i][ks], bg[j][ks], accg[i][j], 0, 0, 0);
                }
        __syncthreads();
    }
    #pragma unroll
    for (int i=0;i<4;i++){
        #pragma unroll
        for (int j=0;j<2;j++){
            #pragma unroll
            for (int reg=0; reg<4; reg++){
                int row = r0 + wr + i*16 + quad*4 + reg;
                int col = j0 + wc + j*16 + lw;
                float a = acca[i][j][reg] + b1[col];
                float g = accg[i][j][reg] + b1[2048+col];
                float gl = 0.5f*g*(1.0f + erff(g*0.70710678118654752f));
                out[(size_t)row*DFFI + col] = f2bf(a*gl);
            }
        }
    }
}

// ---------------- flash attention: GLDS staging, global V^T, no-max softmax ----------------
__global__ __launch_bounds__(256) void attn_fa(
        const short* __restrict__ q, const short* __restrict__ k,
        const short* __restrict__ vt, short* __restrict__ o,
        int Nq, int Nk, int qstr, int kstr, int vtstr, float sc_log2e){
    __shared__ short Ks[64*64];
    __shared__ short Vs[64*64];
    __shared__ short QP[64*64];   // Qs (start) then Ps (loop) — both wave-local rows
    int bh = blockIdx.x & 63;
    int qt = blockIdx.x >> 6;
    int b = bh >> 3, h = bh & 7;
    int tid = threadIdx.x, w = tid>>6, lane = tid&63;
    int quad = lane>>4, lw = lane&15;
    int lrow = lane>>3, lg = (lane&7) ^ (lane>>3);
    int q0 = qt*64;

    #pragma unroll
    for (int t=0;t<2;t++){
        int row = w*16 + t*8 + lrow;
        GLDS(q + (size_t)(b*Nq + q0 + row)*qstr + h*64 + lg*8, QP + (w*16+t*8)*64);
    }
    __syncthreads();
    bf16x8 qf[2];
    {
        int r = w*16 + lw;
        qf[0] = *(const bf16x8*)&QP[r*64 + (( quad      ^ (r&7))*8)];
        qf[1] = *(const bf16x8*)&QP[r*64 + (((quad+4) ^ (r&7))*8)];
    }

    f32x4 oacc[4] = {};
    f32x4 accl = {};
    bf16x8 ones;
    #pragma unroll
    for (int i=0;i<8;i++) ones[i] = (short)0x3F80;

    int nkt = Nk >> 6;
    for (int kt = 0; kt < nkt; kt++){
        __syncthreads();
        #pragma unroll
        for (int t=0;t<2;t++){
            int row = w*16 + t*8 + lrow;
            GLDS(k  + (size_t)(b*Nk + kt*64 + row)*kstr + h*64 + lg*8, Ks + (w*16+t*8)*64);
            GLDS(vt + (size_t)(h*64 + row)*vtstr + b*Nk + kt*64 + lg*8, Vs + (w*16+t*8)*64);
        }
        __syncthreads();

        f32x4 s[4] = {};
        #pragma unroll
        for (int ct=0;ct<4;ct++){
            int r = ct*16 + lw;
            bf16x8 kf0 = *(const bf16x8*)&Ks[r*64 + (( quad      ^ (r&7))*8)];
            bf16x8 kf1 = *(const bf16x8*)&Ks[r*64 + (((quad+4) ^ (r&7))*8)];
            s[ct] = __builtin_amdgcn_mfma_f32_16x16x32_bf16(qf[0], kf0, s[ct], 0,0,0);
            s[ct] = __builtin_amdgcn_mfma_f32_16x16x32_bf16(qf[1], kf1, s[ct], 0,0,0);
        }

        #pragma unroll
        for (int ct=0;ct<4;ct++){
            int colb = (((ct+quad)&3)*16) + lw;
            #pragma unroll
            for (int r=0;r<4;r++){
                float p = exp2f(s[ct][r]*sc_log2e);
                union { float f; unsigned u; } uv; uv.f = p;
                QP[(w*16 + quad*4 + r)*64 + colb] = (short)(uv.u >> 16);
            }
        }
        __asm__ volatile("s_waitcnt lgkmcnt(0)" ::: "memory");

        bf16x8 pf[2];
        {
            int r = w*16 + lw;
            int rot = (lw>>2)&3;
            pf[0] = *(const bf16x8*)&QP[r*64 + (((    (quad>>1) + rot)&3)*16) + (quad&1)*8];
            pf[1] = *(const bf16x8*)&QP[r*64 + (((2 + (quad>>1) + rot)&3)*16) + (quad&1)*8];
        }
        accl = __builtin_amdgcn_mfma_f32_16x16x32_bf16(pf[0], ones, accl, 0,0,0);
        accl = __builtin_amdgcn_mfma_f32_16x16x32_bf16(pf[1], ones, accl, 0,0,0);
        #pragma unroll
        for (int dt=0; dt<4; dt++){
            int r = dt*16 + lw;
            bf16x8 vf0 = *(const bf16x8*)&Vs[r*64 + (( quad      ^ (r&7))*8)];
            bf16x8 vf1 = *(const bf16x8*)&Vs[r*64 + (((quad+4) ^ (r&7))*8)];
            oacc[dt] = __builtin_amdgcn_mfma_f32_16x16x32_bf16(pf[0], vf0, oacc[dt], 0,0,0);
            oacc[dt] = __builtin_amdgcn_mfma_f32_16x16x32_bf16(pf[1], vf1, oacc[dt], 0,0,0);
        }
    }
    float inv[4];
    #pragma unroll
    for (int r=0;r<4;r++) inv[r] = 1.0f/accl[r];
    #pragma unroll
    for (int dt=0; dt<4; dt++){
        #pragma unroll
        for (int r=0;r<4;r++){
            int qi = q0 + w*16 + quad*4 + r;
            o[(size_t)(b*Nq + qi)*512 + h*64 + dt*16 + lw] = f2bf(oacc[dt][r]*inv[r]);
        }
    }
}

extern "C" void kernel_launch(void* const* d_in, const int* in_sizes, int n_in,
                              void* d_out, int out_size, void* d_ws, size_t ws_size,
                              hipStream_t stream) {
    const float* x      = (const float*)d_in[0];
    const float* emb    = (const float*)d_in[1];
    const float* context= (const float*)d_in[2];
    const float* w_emb  = (const float*)d_in[3];
    const float* b_emb  = (const float*)d_in[4];
    const float* gn_g   = (const float*)d_in[5];
    const float* gn_b   = (const float*)d_in[6];
    const float* conv_w = (const float*)d_in[7];
    const float* conv_b = (const float*)d_in[8];
    const float* a1_wq  = (const float*)d_in[9];
    const float* a1_wk  = (const float*)d_in[10];
    const float* a1_wv  = (const float*)d_in[11];
    const float* a1_wo  = (const float*)d_in[12];
    const float* a1_bo  = (const float*)d_in[13];
    const float* a2_wq  = (const float*)d_in[14];
    const float* a2_wk  = (const float*)d_in[15];
    const float* a2_wv  = (const float*)d_in[16];
    const float* a2_wo  = (const float*)d_in[17];
    const float* a2_bo  = (const float*)d_in[18];
    const float* ln1_g  = (const float*)d_in[19];
    const float* ln1_b  = (const float*)d_in[20];
    const float* ln2_g  = (const float*)d_in[21];
    const float* ln2_b  = (const float*)d_in[22];
    const float* ln3_g  = (const float*)d_in[23];
    const float* ln3_b  = (const float*)d_in[24];
    const float* ff_w1  = (const float*)d_in[25];
    const float* ff_b1  = (const float*)d_in[26];
    const float* ff_w2  = (const float*)d_in[27];
    const float* ff_b2  = (const float*)d_in[28];
    float* out = (float*)d_out;

    char* base = (char*)d_ws;
    float* SS    = (float*)base;                 // 8192 f
    float* STATS = SS + 8192;                    // 512 f
    float* F0    = (float*)(base + 65536);       // [8192,512] f32 residual
    float* F1    = F0 + 4194304;
    short* WB    = (short*)(F1 + 4194304);       // bf16 weights, 5505024 shorts
    short* qkW   = WB;                           // [1024,512]: a1_wq, a1_wk
    short* vW    = WB + 524288;                  // [512,512]
    short* wo1W  = WB + 786432;
    short* a2qW  = WB + 1048576;
    short* a2kW  = WB + 1310720;
    short* a2vW  = WB + 1572864;
    short* wo2W  = WB + 1835008;
    short* ffw1W = WB + 2097152;                 // [4096,512]
    short* ffw2W = WB + 4194304;                 // [512,2048]
    short* convW = WB + 5242880;
    short* CTXb  = WB + 5505024;                 // [2048,512]
    short* L0    = CTXb + 1048576;               // [8192,512]
    short* BIG   = L0 + 4194304;                 // multi-purpose
    short* Q0    = BIG;                          // [8192,1024]: q | k
    short* VT1   = BIG + 8388608;                // [512,8192] V^T (self)
    short* AO    = BIG + 12582912;               // [8192,512]
    short* A2Q   = BIG;                          // [8192,512]
    short* K2    = BIG + 4194304;                // [2048,512]
    short* VT2   = BIG + 5242880;                // [512,2048]
    short* ACT2  = BIG;                          // [8192,2048]

    dim3 tb(32,8);
    const float SCL2E = 0.125f * 1.4426950408889634f;

    // ---- weights -> bf16 (one launch) ----
    cvt_all<<<2688,256,0,stream>>>(a1_wq,a1_wk,a1_wv,a1_wo,a2_wq,a2_wk,a2_wv,a2_wo,
                                   ff_w1,ff_w2,conv_w, WB);

    // ---- residual conv branch ----
    emb_gemm<<<32,256,0,stream>>>(emb, w_emb, b_emb, SS);
    gn_stats<<<256,256,0,stream>>>(x, STATS);
    mod_act<<<dim3(32,16,8), tb, 0, stream>>>(x, STATS, gn_g, gn_b, SS, L0);
    transpose_ctx<<<dim3(8,16,8), tb, 0, stream>>>(context, CTXb);
    gemm64<<<dim3(128,8),256,0,stream>>>(L0, convW, conv_b, x, F0, nullptr, 512, 512, 512, 2);  // xt0=F0

    // ---- self attention ----
    ln_rows<<<2048,256,0,stream>>>(F0, ln1_g, ln1_b, L0);
    gemm_bb<<<dim3(64,16),256,0,stream>>>(L0, qkW, nullptr, nullptr, nullptr, Q0, 512, 1024, 1024, 0);
    gemm64<<<dim3(8,128),256,0,stream>>>(vW, L0, nullptr, nullptr, nullptr, VT1, 512, 8192, 8192, 0); // V^T
    attn_fa<<<1024,256,0,stream>>>(Q0, Q0+512, VT1, AO, 1024, 1024, 1024, 1024, 8192, SCL2E);
    gemm64<<<dim3(128,8),256,0,stream>>>(AO, wo1W, a1_bo, F0, F1, nullptr, 512, 512, 512, 1);   // xt1=F1

    // ---- cross attention ----
    ln_rows<<<2048,256,0,stream>>>(F1, ln2_g, ln2_b, L0);
    gemm64<<<dim3(128,8),256,0,stream>>>(L0, a2qW, nullptr, nullptr, nullptr, A2Q, 512, 512, 512, 0);
    gemm64<<<dim3(32,8),256,0,stream>>>(CTXb, a2kW, nullptr, nullptr, nullptr, K2, 512, 512, 512, 0);
    gemm64<<<dim3(8,32),256,0,stream>>>(a2vW, CTXb, nullptr, nullptr, nullptr, VT2, 512, 2048, 2048, 0); // V^T
    attn_fa<<<1024,256,0,stream>>>(A2Q, K2, VT2, AO, 1024, 256, 512, 512, 2048, SCL2E);
    gemm64<<<dim3(128,8),256,0,stream>>>(AO, wo2W, a2_bo, F1, F0, nullptr, 512, 512, 512, 1);   // xt2=F0

    // ---- GEGLU FF ----
    ln_rows<<<2048,256,0,stream>>>(F0, ln3_g, ln3_b, L0);
    ff1_geglu_bb<<<dim3(64,32),256,0,stream>>>(L0, ffw1W, ff_b1, ACT2);
    gemm64<<<dim3(128,8),256,0,stream>>>(ACT2, ffw2W, ff_b2, F0, F1, nullptr, 2048, 512, 512, 1);
    transpose_out<<<dim3(32,16,8), tb, 0, stream>>>(F1, out);
}

// Round 8
// 427.190 us; speedup vs baseline: 1.0996x; 1.0341x over previous
//
#include <hip/hip_runtime.h>
#include <math.h>

#define NB 8
#define CDIM 512
#define NT 1024
#define MT 256
#define DFFI 2048   // GEGLU inner half

typedef short bf16x8 __attribute__((ext_vector_type(8)));
typedef float f32x4 __attribute__((ext_vector_type(4)));

__device__ __forceinline__ float sigmoidf_(float v){ return 1.0f/(1.0f+__expf(-v)); }

__device__ __forceinline__ short f2bf(float f){
    union { float f; unsigned u; } v; v.f = f;
    unsigned r = v.u + 0x7FFFu + ((v.u >> 16) & 1u);
    return (short)(r >> 16);
}

// pack two f32 into one u32 of 2 bf16 (truncation): lo -> low short, hi -> high short
__device__ __forceinline__ unsigned pk2bf(float lo, float hi){
    union { float f; unsigned u; } a, b; a.f = lo; b.f = hi;
    return (a.u >> 16) | (b.u & 0xFFFF0000u);
}

#define GLDS(gp, lp) __builtin_amdgcn_global_load_lds( \
    (const __attribute__((address_space(1))) void*)(gp), \
    (__attribute__((address_space(3))) void*)(lp), 16, 0, 0)

// ---------------- fused f32 -> bf16 weight conversion (single launch) ----------------
__global__ void cvt_all(const float* __restrict__ a1wq, const float* __restrict__ a1wk,
                        const float* __restrict__ a1wv, const float* __restrict__ a1wo,
                        const float* __restrict__ a2wq, const float* __restrict__ a2wk,
                        const float* __restrict__ a2wv, const float* __restrict__ a2wo,
                        const float* __restrict__ ffw1, const float* __restrict__ ffw2,
                        const float* __restrict__ convw, short* __restrict__ WB){
    int e = (blockIdx.x*256 + threadIdx.x)*8;
    if (e >= 5505024) return;
    const float* src; int off;
    if (e < 2097152){
        const float* tbl[8] = {a1wq,a1wk,a1wv,a1wo,a2wq,a2wk,a2wv,a2wo};
        src = tbl[e >> 18]; off = e & 262143;
    } else if (e < 4194304){ src = ffw1; off = e - 2097152; }
    else if (e < 5242880){ src = ffw2; off = e - 4194304; }
    else { src = convw; off = e - 5242880; }
    float4 x0 = ((const float4*)(src+off))[0], x1 = ((const float4*)(src+off))[1];
    bf16x8 v;
    v[0]=f2bf(x0.x); v[1]=f2bf(x0.y); v[2]=f2bf(x0.z); v[3]=f2bf(x0.w);
    v[4]=f2bf(x1.x); v[5]=f2bf(x1.y); v[6]=f2bf(x1.z); v[7]=f2bf(x1.w);
    *(bf16x8*)(WB + e) = v;
}

// ---------------- small elementwise / norm kernels ----------------

__global__ void emb_gemm(const float* __restrict__ emb, const float* __restrict__ w,
                         const float* __restrict__ bias, float* __restrict__ out){
    int idx = blockIdx.x*256 + threadIdx.x;   // 8*1024 total
    int b = idx >> 10, o = idx & 1023;
    const float* e = emb + b*128;
    const float* wr = w + (size_t)o*128;
    float acc = 0.f;
    for (int i=0;i<128;i++){ float ev=e[i]; acc += (ev*sigmoidf_(ev))*wr[i]; }
    out[idx] = acc + bias[o];
}

__global__ void gn_stats(const float* __restrict__ x, float* __restrict__ stats){
    int bg = blockIdx.x;               // b*32+g
    const float* base = x + (size_t)bg*16*NT;
    float s=0.f, sq=0.f;
    for (int i=threadIdx.x; i<16*NT; i+=256){ float v = base[i]; s+=v; sq+=v*v; }
    __shared__ float rs[256], rq[256];
    rs[threadIdx.x]=s; rq[threadIdx.x]=sq; __syncthreads();
    for (int st=128; st>0; st>>=1){
        if (threadIdx.x<st){ rs[threadIdx.x]+=rs[threadIdx.x+st]; rq[threadIdx.x]+=rq[threadIdx.x+st]; }
        __syncthreads();
    }
    if (threadIdx.x==0){
        float mu = rs[0]/(16.f*NT);
        float var = rq[0]/(16.f*NT) - mu*mu;
        stats[2*bg] = mu; stats[2*bg+1] = rsqrtf(var + 1e-6f);
    }
}

__global__ void mod_act(const float* __restrict__ x, const float* __restrict__ stats,
                        const float* __restrict__ gg, const float* __restrict__ gb,
                        const float* __restrict__ ss, short* __restrict__ act_t){
    __shared__ float tile[32][33];
    int n0 = blockIdx.x*32, c0 = blockIdx.y*32, b = blockIdx.z;
    int tx = threadIdx.x, ty = threadIdx.y;
    #pragma unroll
    for (int k=0;k<4;k++){
        int c = c0 + ty + k*8;
        tile[ty+k*8][tx] = x[((size_t)(b*CDIM+c))*NT + n0 + tx];
    }
    __syncthreads();
    #pragma unroll
    for (int k=0;k<4;k++){
        int c = c0 + tx, n = n0 + ty + k*8;
        float raw = tile[tx][ty+k*8];
        int gi = b*32 + (c>>4);
        float v = (raw - stats[2*gi]) * stats[2*gi+1] * gg[c] + gb[c];
        v = v * (1.f + ss[b*1024 + c]) + ss[b*1024 + 512 + c];
        act_t[((size_t)(b*NT+n))*CDIM + c] = f2bf(v * sigmoidf_(v));
    }
}

// LayerNorm: one wave per row (512 cols), 4 rows/block, shuffle reduce
__global__ void ln_rows(const float* __restrict__ in, const float* __restrict__ g,
                        const float* __restrict__ bta, short* __restrict__ out){
    int row = blockIdx.x*4 + (threadIdx.x>>6);
    int lane = threadIdx.x & 63;
    const float* base = in + (size_t)row*CDIM + lane*8;
    float4 a = ((const float4*)base)[0], b4 = ((const float4*)base)[1];
    float vals[8] = {a.x,a.y,a.z,a.w,b4.x,b4.y,b4.z,b4.w};
    float s = 0.f, q = 0.f;
    #pragma unroll
    for (int i=0;i<8;i++){ s += vals[i]; q += vals[i]*vals[i]; }
    #pragma unroll
    for (int off=32; off>0; off>>=1){ s += __shfl_xor(s, off); q += __shfl_xor(q, off); }
    float mu = s*(1.f/512.f);
    float rstd = rsqrtf(q*(1.f/512.f) - mu*mu + 1e-5f);
    const float* gp = g + lane*8;
    const float* bp = bta + lane*8;
    float4 g0=((const float4*)gp)[0], g1=((const float4*)gp)[1];
    float4 e0=((const float4*)bp)[0], e1=((const float4*)bp)[1];
    float gs[8] = {g0.x,g0.y,g0.z,g0.w,g1.x,g1.y,g1.z,g1.w};
    float es[8] = {e0.x,e0.y,e0.z,e0.w,e1.x,e1.y,e1.z,e1.w};
    bf16x8 o8;
    #pragma unroll
    for (int i=0;i<8;i++) o8[i] = f2bf((vals[i]-mu)*rstd*gs[i] + es[i]);
    *(bf16x8*)(out + (size_t)row*CDIM + lane*8) = o8;
}

__global__ void transpose_ctx(const float* __restrict__ in, short* __restrict__ out){
    __shared__ float tile[32][33];
    int m0 = blockIdx.x*32, c0 = blockIdx.y*32, b = blockIdx.z;
    int tx=threadIdx.x, ty=threadIdx.y;
    #pragma unroll
    for (int k=0;k<4;k++){
        int c = c0+ty+k*8;
        tile[ty+k*8][tx] = in[((size_t)(b*512+c))*MT + m0+tx];
    }
    __syncthreads();
    #pragma unroll
    for (int k=0;k<4;k++){
        int m = m0+ty+k*8, c = c0+tx;
        out[((size_t)(b*MT+m))*512 + c] = f2bf(tile[tx][ty+k*8]);
    }
}

__global__ void transpose_out(const float* __restrict__ in, float* __restrict__ out){
    __shared__ float tile[32][33];
    int n0 = blockIdx.x*32, c0 = blockIdx.y*32, b=blockIdx.z;
    int tx=threadIdx.x, ty=threadIdx.y;
    #pragma unroll
    for (int k=0;k<4;k++){
        int n = n0+ty+k*8;
        tile[ty+k*8][tx] = in[((size_t)(b*NT+n))*512 + c0+tx];
    }
    __syncthreads();
    #pragma unroll
    for (int k=0;k<4;k++){
        int c = c0+ty+k*8, n = n0+tx;
        out[((size_t)(b*512+c))*NT + n] = tile[tx][ty+k*8];
    }
}

// ---------------- bf16 GEMM: 128x64 tile, BK=64, single-buffered GLDS (for wide-O) ----------------
__global__ __launch_bounds__(256,2) void gemm_bb(
        const short* __restrict__ A, const short* __restrict__ W,
        const float* __restrict__ bias, const float* __restrict__ res,
        float* __restrict__ outf, short* __restrict__ outb,
        int K, int O, int ostr, int resmode){
    __shared__ short As[128*64];
    __shared__ short Bs[64*64];
    int r0 = blockIdx.x*128, o0 = blockIdx.y*64;
    int tid = threadIdx.x, w = tid>>6, lane = tid&63;
    int quad = lane>>4, lw = lane&15;
    int g_row = lane>>3, g_s = lane&7;
    int sseg = g_s ^ g_row;
    int wr = (w&1)*64, wc = (w>>1)*32;
    f32x4 acc[4][2] = {};
    for (int k0 = 0; k0 < K; k0 += 64){
        #pragma unroll
        for (int j=0;j<4;j++){
            int row = w*32 + j*8 + g_row;
            GLDS(A + (size_t)(r0+row)*K + k0 + sseg*8, As + (w*32+j*8)*64);
        }
        #pragma unroll
        for (int j=0;j<2;j++){
            int row = w*16 + j*8 + g_row;
            GLDS(W + (size_t)(o0+row)*K + k0 + sseg*8, Bs + (w*16+j*8)*64);
        }
        __syncthreads();
        bf16x8 af[4][2], bf[2][2];
        #pragma unroll
        for (int ks=0; ks<2; ks++){
            #pragma unroll
            for (int i=0;i<4;i++){
                int row = wr + i*16 + lw;
                af[i][ks] = *(const bf16x8*)&As[row*64 + (((ks*4+quad) ^ (lw&7)))*8];
            }
            #pragma unroll
            for (int j=0;j<2;j++){
                int col = wc + j*16 + lw;
                bf[j][ks] = *(const bf16x8*)&Bs[col*64 + (((ks*4+quad) ^ (lw&7)))*8];
            }
        }
        #pragma unroll
        for (int ks=0; ks<2; ks++)
            #pragma unroll
            for (int i=0;i<4;i++)
                #pragma unroll
                for (int j=0;j<2;j++)
                    acc[i][j] = __builtin_amdgcn_mfma_f32_16x16x32_bf16(af[i][ks], bf[j][ks], acc[i][j], 0, 0, 0);
        __syncthreads();
    }
    #pragma unroll
    for (int i=0;i<4;i++){
        #pragma unroll
        for (int j=0;j<2;j++){
            #pragma unroll
            for (int reg=0; reg<4; reg++){
                int row = r0 + wr + i*16 + quad*4 + reg;
                int col = o0 + wc + j*16 + lw;
                float v = acc[i][j][reg];
                if (bias) v += bias[col];
                if (resmode==1) v += res[(size_t)row*O + col];
                else if (resmode==2){
                    int b = row >> 10, n = row & 1023;
                    v += res[((size_t)(b*CDIM+col))*NT + n];
                }
                if (outf) outf[(size_t)row*ostr + col] = v;
                else      outb[(size_t)row*ostr + col] = f2bf(v);
            }
        }
    }
}

// ---------------- bf16 GEMM: 64x64 tile, BK=64 — max block-count for skinny outputs ----------------
__global__ __launch_bounds__(256) void gemm64(
        const short* __restrict__ A, const short* __restrict__ W,
        const float* __restrict__ bias, const float* __restrict__ res,
        float* __restrict__ outf, short* __restrict__ outb,
        int K, int O, int ostr, int resmode){
    __shared__ short As[64*64];
    __shared__ short Bs[64*64];
    int r0 = blockIdx.x*64, o0 = blockIdx.y*64;
    int tid = threadIdx.x, w = tid>>6, lane = tid&63;
    int quad = lane>>4, lw = lane&15;
    int lrow = lane>>3, lg = (lane&7) ^ (lane>>3);
    int wr = (w&1)*32, wc = (w>>1)*32;
    f32x4 acc[2][2] = {};
    for (int k0 = 0; k0 < K; k0 += 64){
        #pragma unroll
        for (int t=0;t<2;t++){
            int row = w*16 + t*8 + lrow;
            GLDS(A + (size_t)(r0+row)*K + k0 + lg*8, As + (w*16+t*8)*64);
            GLDS(W + (size_t)(o0+row)*K + k0 + lg*8, Bs + (w*16+t*8)*64);
        }
        __syncthreads();
        bf16x8 af[2][2], bf[2][2];
        #pragma unroll
        for (int ks=0; ks<2; ks++){
            #pragma unroll
            for (int i=0;i<2;i++){
                int row = wr + i*16 + lw;
                af[i][ks] = *(const bf16x8*)&As[row*64 + (((ks*4+quad) ^ (lw&7)))*8];
                int col = wc + i*16 + lw;
                bf[i][ks] = *(const bf16x8*)&Bs[col*64 + (((ks*4+quad) ^ (lw&7)))*8];
            }
        }
        #pragma unroll
        for (int ks=0; ks<2; ks++)
            #pragma unroll
            for (int i=0;i<2;i++)
                #pragma unroll
                for (int j=0;j<2;j++)
                    acc[i][j] = __builtin_amdgcn_mfma_f32_16x16x32_bf16(af[i][ks], bf[j][ks], acc[i][j], 0, 0, 0);
        __syncthreads();
    }
    #pragma unroll
    for (int i=0;i<2;i++){
        #pragma unroll
        for (int j=0;j<2;j++){
            #pragma unroll
            for (int reg=0; reg<4; reg++){
                int row = r0 + wr + i*16 + quad*4 + reg;
                int col = o0 + wc + j*16 + lw;
                float v = acc[i][j][reg];
                if (bias) v += bias[col];
                if (resmode==1) v += res[(size_t)row*O + col];
                else if (resmode==2){
                    int b = row >> 10, n = row & 1023;
                    v += res[((size_t)(b*CDIM+col))*NT + n];
                }
                if (outf) outf[(size_t)row*ostr + col] = v;
                else      outb[(size_t)row*ostr + col] = f2bf(v);
            }
        }
    }
}

// ---------------- FF1 fused GEGLU, 128x64 tile (x2 gates), BK=64 ----------------
__global__ __launch_bounds__(256,2) void ff1_geglu_bb(
        const short* __restrict__ A, const short* __restrict__ W,
        const float* __restrict__ b1, short* __restrict__ out){
    __shared__ short As[128*64];
    __shared__ short Ba[64*64];
    __shared__ short Bg[64*64];
    int r0 = blockIdx.x*128, j0 = blockIdx.y*64;
    int tid = threadIdx.x, w = tid>>6, lane = tid&63;
    int quad = lane>>4, lw = lane&15;
    int g_row = lane>>3, g_s = lane&7;
    int sseg = g_s ^ g_row;
    int wr = (w&1)*64, wc = (w>>1)*32;
    f32x4 acca[4][2] = {}, accg[4][2] = {};
    for (int k0 = 0; k0 < 512; k0 += 64){
        #pragma unroll
        for (int j=0;j<4;j++){
            int row = w*32 + j*8 + g_row;
            GLDS(A + (size_t)(r0+row)*512 + k0 + sseg*8, As + (w*32+j*8)*64);
        }
        #pragma unroll
        for (int j=0;j<2;j++){
            int row = w*16 + j*8 + g_row;
            GLDS(W + (size_t)(j0+row)*512 + k0 + sseg*8, Ba + (w*16+j*8)*64);
            GLDS(W + (size_t)(2048+j0+row)*512 + k0 + sseg*8, Bg + (w*16+j*8)*64);
        }
        __syncthreads();
        bf16x8 af[4][2], ba[2][2], bg[2][2];
        #pragma unroll
        for (int ks=0; ks<2; ks++){
            #pragma unroll
            for (int i=0;i<4;i++){
                int row = wr + i*16 + lw;
                af[i][ks] = *(const bf16x8*)&As[row*64 + (((ks*4+quad) ^ (lw&7)))*8];
            }
            #pragma unroll
            for (int j=0;j<2;j++){
                int col = wc + j*16 + lw;
                ba[j][ks] = *(const bf16x8*)&Ba[col*64 + (((ks*4+quad) ^ (lw&7)))*8];
                bg[j][ks] = *(const bf16x8*)&Bg[col*64 + (((ks*4+quad) ^ (lw&7)))*8];
            }
        }
        #pragma unroll
        for (int ks=0; ks<2; ks++)
            #pragma unroll
            for (int i=0;i<4;i++)
                #pragma unroll
                for (int j=0;j<2;j++){
                    acca[i][j] = __builtin_amdgcn_mfma_f32_16x16x32_bf16(af[i][ks], ba[j][ks], acca[i][j], 0, 0, 0);
                    accg[i][j] = __builtin_amdgcn_mfma_f32_16x16x32_bf16(af[i][ks], bg[j][ks], accg[i][j], 0, 0, 0);
                }
        __syncthreads();
    }
    #pragma unroll
    for (int i=0;i<4;i++){
        #pragma unroll
        for (int j=0;j<2;j++){
            #pragma unroll
            for (int reg=0; reg<4; reg++){
                int row = r0 + wr + i*16 + quad*4 + reg;
                int col = j0 + wc + j*16 + lw;
                float a = acca[i][j][reg] + b1[col];
                float g = accg[i][j][reg] + b1[2048+col];
                float gl = 0.5f*g*(1.0f + erff(g*0.70710678118654752f));
                out[(size_t)row*DFFI + col] = f2bf(a*gl);
            }
        }
    }
}

// ---------------- flash attention v2: S^T MFMA, register-resident P (no LDS round-trip) ----------------
// S^T = mfma(A=K, B=Q): lane holds P^T[key=ct*16+quad*4+r][query=w*16+lw].
// Packing ct-pairs gives a valid PV A-operand (k=quad*8+j <-> key bijection);
// V B-fragment gathered with the matching key map via 2x ds_read_b64 from Vs[d][key].
__global__ __launch_bounds__(256) void attn_fa(
        const short* __restrict__ q, const short* __restrict__ k,
        const short* __restrict__ vt, short* __restrict__ o,
        int Nq, int Nk, int qstr, int kstr, int vtstr, float sc_log2e){
    __shared__ short Ks[64*64];
    __shared__ short Vs[64*64];
    __shared__ short Qs[64*64];
    int bh = blockIdx.x & 63;
    int qt = blockIdx.x >> 6;
    int b = bh >> 3, h = bh & 7;
    int tid = threadIdx.x, w = tid>>6, lane = tid&63;
    int quad = lane>>4, lw = lane&15;
    int lrow = lane>>3, lg = (lane&7) ^ (lane>>3);
    int q0 = qt*64;

    #pragma unroll
    for (int t=0;t<2;t++){
        int row = w*16 + t*8 + lrow;
        GLDS(q + (size_t)(b*Nq + q0 + row)*qstr + h*64 + lg*8, Qs + (w*16+t*8)*64);
    }
    __syncthreads();
    bf16x8 qf[2];
    {
        int r = w*16 + lw;
        qf[0] = *(const bf16x8*)&Qs[r*64 + (( quad    ^ (r&7))*8)];
        qf[1] = *(const bf16x8*)&Qs[r*64 + (((quad+4) ^ (r&7))*8)];
    }

    f32x4 oacc[4] = {};
    f32x4 accl = {};
    bf16x8 ones;
    #pragma unroll
    for (int i=0;i<8;i++) ones[i] = (short)0x3F80;

    int x7 = lw&7;
    int nkt = Nk >> 6;
    for (int kt = 0; kt < nkt; kt++){
        __syncthreads();
        #pragma unroll
        for (int t=0;t<2;t++){
            int row = w*16 + t*8 + lrow;
            GLDS(k  + (size_t)(b*Nk + kt*64 + row)*kstr + h*64 + lg*8, Ks + (w*16+t*8)*64);
            GLDS(vt + (size_t)(h*64 + row)*vtstr + b*Nk + kt*64 + lg*8, Vs + (w*16+t*8)*64);
        }
        __syncthreads();

        // S^T[key][query]: A = K-fragment (m=key), B = Q-fragment (n=query)
        f32x4 s[4];
        #pragma unroll
        for (int ct=0;ct<4;ct++){
            int r = ct*16 + lw;
            bf16x8 kf0 = *(const bf16x8*)&Ks[r*64 + (( quad    ^ (r&7))*8)];
            bf16x8 kf1 = *(const bf16x8*)&Ks[r*64 + (((quad+4) ^ (r&7))*8)];
            f32x4 z = {};
            z = __builtin_amdgcn_mfma_f32_16x16x32_bf16(kf0, qf[0], z, 0,0,0);
            s[ct] = __builtin_amdgcn_mfma_f32_16x16x32_bf16(kf1, qf[1], z, 0,0,0);
        }
        // P = exp2(S*scale) in registers, pack ct-pairs into PV A-fragments
        float pe[4][4];
        #pragma unroll
        for (int ct=0;ct<4;ct++)
            #pragma unroll
            for (int r=0;r<4;r++) pe[ct][r] = exp2f(s[ct][r]*sc_log2e);
        union { bf16x8 v; unsigned u[4]; } pa[2];
        #pragma unroll
        for (int pr=0;pr<2;pr++){
            pa[pr].u[0] = pk2bf(pe[pr*2  ][0], pe[pr*2  ][1]);
            pa[pr].u[1] = pk2bf(pe[pr*2  ][2], pe[pr*2  ][3]);
            pa[pr].u[2] = pk2bf(pe[pr*2+1][0], pe[pr*2+1][1]);
            pa[pr].u[3] = pk2bf(pe[pr*2+1][2], pe[pr*2+1][3]);
        }
        // l += P.1
        accl = __builtin_amdgcn_mfma_f32_16x16x32_bf16(pa[0].v, ones, accl, 0,0,0);
        accl = __builtin_amdgcn_mfma_f32_16x16x32_bf16(pa[1].v, ones, accl, 0,0,0);
        // O += P.V : B-fragment = V rows d=dt*16+lw, keys matching A's k-map
        #pragma unroll
        for (int dt=0; dt<4; dt++){
            int rb = (dt*16 + lw)*64;
            #pragma unroll
            for (int pr=0;pr<2;pr++){
                int gl  = pr*4 + (quad>>1);
                int off = (quad&1)*4;
                union { bf16x8 v; unsigned long long d[2]; } vb;
                vb.d[0] = *(const unsigned long long*)&Vs[rb + (( gl    ^ x7)<<3) + off];
                vb.d[1] = *(const unsigned long long*)&Vs[rb + (((gl+2) ^ x7)<<3) + off];
                oacc[dt] = __builtin_amdgcn_mfma_f32_16x16x32_bf16(pa[pr].v, vb.v, oacc[dt], 0,0,0);
            }
        }
    }
    float inv[4];
    #pragma unroll
    for (int r=0;r<4;r++) inv[r] = 1.0f/accl[r];
    #pragma unroll
    for (int dt=0; dt<4; dt++){
        #pragma unroll
        for (int r=0;r<4;r++){
            int qi = q0 + w*16 + quad*4 + r;
            o[(size_t)(b*Nq + qi)*512 + h*64 + dt*16 + lw] = f2bf(oacc[dt][r]*inv[r]);
        }
    }
}

extern "C" void kernel_launch(void* const* d_in, const int* in_sizes, int n_in,
                              void* d_out, int out_size, void* d_ws, size_t ws_size,
                              hipStream_t stream) {
    const float* x      = (const float*)d_in[0];
    const float* emb    = (const float*)d_in[1];
    const float* context= (const float*)d_in[2];
    const float* w_emb  = (const float*)d_in[3];
    const float* b_emb  = (const float*)d_in[4];
    const float* gn_g   = (const float*)d_in[5];
    const float* gn_b   = (const float*)d_in[6];
    const float* conv_w = (const float*)d_in[7];
    const float* conv_b = (const float*)d_in[8];
    const float* a1_wq  = (const float*)d_in[9];
    const float* a1_wk  = (const float*)d_in[10];
    const float* a1_wv  = (const float*)d_in[11];
    const float* a1_wo  = (const float*)d_in[12];
    const float* a1_bo  = (const float*)d_in[13];
    const float* a2_wq  = (const float*)d_in[14];
    const float* a2_wk  = (const float*)d_in[15];
    const float* a2_wv  = (const float*)d_in[16];
    const float* a2_wo  = (const float*)d_in[17];
    const float* a2_bo  = (const float*)d_in[18];
    const float* ln1_g  = (const float*)d_in[19];
    const float* ln1_b  = (const float*)d_in[20];
    const float* ln2_g  = (const float*)d_in[21];
    const float* ln2_b  = (const float*)d_in[22];
    const float* ln3_g  = (const float*)d_in[23];
    const float* ln3_b  = (const float*)d_in[24];
    const float* ff_w1  = (const float*)d_in[25];
    const float* ff_b1  = (const float*)d_in[26];
    const float* ff_w2  = (const float*)d_in[27];
    const float* ff_b2  = (const float*)d_in[28];
    float* out = (float*)d_out;

    char* base = (char*)d_ws;
    float* SS    = (float*)base;                 // 8192 f
    float* STATS = SS + 8192;                    // 512 f
    float* F0    = (float*)(base + 65536);       // [8192,512] f32 residual
    float* F1    = F0 + 4194304;
    short* WB    = (short*)(F1 + 4194304);       // bf16 weights, 5505024 shorts
    short* qkW   = WB;                           // [1024,512]: a1_wq, a1_wk
    short* vW    = WB + 524288;                  // [512,512]
    short* wo1W  = WB + 786432;
    short* a2qW  = WB + 1048576;
    short* a2kW  = WB + 1310720;
    short* a2vW  = WB + 1572864;
    short* wo2W  = WB + 1835008;
    short* ffw1W = WB + 2097152;                 // [4096,512]
    short* ffw2W = WB + 4194304;                 // [512,2048]
    short* convW = WB + 5242880;
    short* CTXb  = WB + 5505024;                 // [2048,512]
    short* L0    = CTXb + 1048576;               // [8192,512]
    short* BIG   = L0 + 4194304;                 // multi-purpose
    short* Q0    = BIG;                          // [8192,1024]: q | k
    short* VT1   = BIG + 8388608;                // [512,8192] V^T (self)
    short* AO    = BIG + 12582912;               // [8192,512]
    short* A2Q   = BIG;                          // [8192,512]
    short* K2    = BIG + 4194304;                // [2048,512]
    short* VT2   = BIG + 5242880;                // [512,2048]
    short* ACT2  = BIG;                          // [8192,2048]

    dim3 tb(32,8);
    const float SCL2E = 0.125f * 1.4426950408889634f;

    // ---- weights -> bf16 (one launch) ----
    cvt_all<<<2688,256,0,stream>>>(a1_wq,a1_wk,a1_wv,a1_wo,a2_wq,a2_wk,a2_wv,a2_wo,
                                   ff_w1,ff_w2,conv_w, WB);

    // ---- residual conv branch ----
    emb_gemm<<<32,256,0,stream>>>(emb, w_emb, b_emb, SS);
    gn_stats<<<256,256,0,stream>>>(x, STATS);
    mod_act<<<dim3(32,16,8), tb, 0, stream>>>(x, STATS, gn_g, gn_b, SS, L0);
    transpose_ctx<<<dim3(8,16,8), tb, 0, stream>>>(context, CTXb);
    gemm64<<<dim3(128,8),256,0,stream>>>(L0, convW, conv_b, x, F0, nullptr, 512, 512, 512, 2);  // xt0=F0

    // ---- self attention ----
    ln_rows<<<2048,256,0,stream>>>(F0, ln1_g, ln1_b, L0);
    gemm_bb<<<dim3(64,16),256,0,stream>>>(L0, qkW, nullptr, nullptr, nullptr, Q0, 512, 1024, 1024, 0);
    gemm64<<<dim3(8,128),256,0,stream>>>(vW, L0, nullptr, nullptr, nullptr, VT1, 512, 8192, 8192, 0); // V^T
    attn_fa<<<1024,256,0,stream>>>(Q0, Q0+512, VT1, AO, 1024, 1024, 1024, 1024, 8192, SCL2E);
    gemm64<<<dim3(128,8),256,0,stream>>>(AO, wo1W, a1_bo, F0, F1, nullptr, 512, 512, 512, 1);   // xt1=F1

    // ---- cross attention ----
    ln_rows<<<2048,256,0,stream>>>(F1, ln2_g, ln2_b, L0);
    gemm64<<<dim3(128,8),256,0,stream>>>(L0, a2qW, nullptr, nullptr, nullptr, A2Q, 512, 512, 512, 0);
    gemm64<<<dim3(32,8),256,0,stream>>>(CTXb, a2kW, nullptr, nullptr, nullptr, K2, 512, 512, 512, 0);
    gemm64<<<dim3(8,32),256,0,stream>>>(a2vW, CTXb, nullptr, nullptr, nullptr, VT2, 512, 2048, 2048, 0); // V^T
    attn_fa<<<1024,256,0,stream>>>(A2Q, K2, VT2, AO, 1024, 256, 512, 512, 2048, SCL2E);
    gemm64<<<dim3(128,8),256,0,stream>>>(AO, wo2W, a2_bo, F1, F0, nullptr, 512, 512, 512, 1);   // xt2=F0

    // ---- GEGLU FF ----
    ln_rows<<<2048,256,0,stream>>>(F0, ln3_g, ln3_b, L0);
    ff1_geglu_bb<<<dim3(64,32),256,0,stream>>>(L0, ffw1W, ff_b1, ACT2);
    gemm64<<<dim3(128,8),256,0,stream>>>(ACT2, ffw2W, ff_b2, F0, F1, nullptr, 2048, 512, 512, 1);
    transpose_out<<<dim3(32,16,8), tb, 0, stream>>>(F1, out);
}